// Round 3
// baseline (926.953 us; speedup 1.0000x reference)
//
#include <hip/hip_runtime.h>
#include <math.h>

#define EPS 1e-6f
#define NE 64
#define TPB 1024
#define WPB 16             // waves per block
#define NBLK 512           // == 2 blocks/CU: 32 waves/CU (full wave slots)
#define NWAVES (NBLK * WPB)   // 8192
#define ITERS 10
#define PF 4               // prefetch depth (quads per batch)

// ---- DPP helpers: 16-lane-group reductions, pure VALU (no ds ops) ----
template <int ctrl>
__device__ __forceinline__ float dppf(float x) {
    return __int_as_float(__builtin_amdgcn_update_dpp(
        0, __float_as_int(x), ctrl, 0xf, 0xf, true));
}
template <int ctrl>
__device__ __forceinline__ int dppi(int x) {
    return __builtin_amdgcn_update_dpp(0, x, ctrl, 0xf, 0xf, true);
}

__device__ __forceinline__ float group16_sum(float v) {
    v += dppf<0xB1>(v);   // quad_perm xor 1
    v += dppf<0x4E>(v);   // quad_perm xor 2
    v += dppf<0x141>(v);  // row_half_mirror (xor 4)
    v += dppf<0x140>(v);  // row_mirror (xor 8)
    return v;
}

#define ARGMAX_STEP(CTRL)                                      \
    {                                                          \
        float ov = dppf<CTRL>(v);                              \
        int oi = dppi<CTRL>(i);                                \
        if (ov > v || (ov == v && oi < i)) { v = ov; i = oi; } \
    }

__device__ __forceinline__ void group16_argmax(float& v, int& i) {
    ARGMAX_STEP(0xB1)
    ARGMAX_STEP(0x4E)
    ARGMAX_STEP(0x141)
    ARGMAX_STEP(0x140)
}

// Persistent fused kernel, round 3: same minimal-fence barrier as R2
// (validated: 403us kernel), occupancy 1 -> 2 blocks/CU.
// R2 post-mortem: VALUBusy 31%, HBM 23%, occupancy 47% -> latency-bound at
// 4 waves/SIMD. NBLK=512 + __launch_bounds__(1024,8) gives 32 waves/CU
// (LDS 2x28.5KB=57KB ok, VGPR 36<=64 ok). Reduction orders unchanged ->
// bitwise-identical output.
__global__ __launch_bounds__(TPB, 8) void sink_fused(
    const float4* __restrict__ logits4,
    float* __restrict__ Pblk,          // [2][NBLK][NE]
    unsigned* __restrict__ counters,   // [ITERS]
    float2* __restrict__ oidx, float2* __restrict__ ow,
    int nquads, float col_target) {
    __shared__ float4 plds[WPB][64];   // 16 KB  block column-partial buffer
    __shared__ float s_red[16][NE];    // 4 KB   chunk-reduce buffer
    __shared__ float r_lds[WPB * 64];  // 4 KB   per-row r (1024 rows/block)
    __shared__ float4 c_lds4[NE / 4];  // 256 B  current column scaling

    const int tid = threadIdx.x;
    const int lane = tid & 63;
    const int wib = tid >> 6;
    const int g = lane >> 4;   // row within quad
    const int h = lane & 15;   // float4 slot within row
    const int qpw = nquads / NWAVES;                 // 16
    const int qbase = (blockIdx.x * WPB + wib) * qpw;
    const float4* lp = logits4 + (size_t)qbase * 64 + lane;
    const int nb = qpw / PF;                         // 4
    const int lrow0 = wib * 64 + g;

    if (tid < NE / 4) c_lds4[tid] = make_float4(1.f, 1.f, 1.f, 1.f);
    __syncthreads();

    for (int it = 0; it < ITERS; ++it) {
        const float4 c4 = c_lds4[h];
        float* Pcur = Pblk + (size_t)(it & 1) * NBLK * NE;

        float4 buf[PF];
#pragma unroll
        for (int p = 0; p < PF; ++p) buf[p] = lp[(size_t)p * 64];

        float4 pacc = {0.f, 0.f, 0.f, 0.f};
        for (int b = 0; b < nb; ++b) {
            float4 cur[PF];
#pragma unroll
            for (int p = 0; p < PF; ++p) cur[p] = buf[p];
            if (b + 1 < nb) {
                const float4* np = lp + (size_t)(b + 1) * PF * 64;
#pragma unroll
                for (int p = 0; p < PF; ++p) buf[p] = np[(size_t)p * 64];
            }
#pragma unroll
            for (int p = 0; p < PF; ++p) {
                float4 q;
                q.x = __expf(cur[p].x); q.y = __expf(cur[p].y);
                q.z = __expf(cur[p].z); q.w = __expf(cur[p].w);
                float s = q.x * c4.x + q.y * c4.y + q.z * c4.z + q.w * c4.w;
                s = group16_sum(s);
                const int lrow = lrow0 + (b * PF + p) * 4;
                float rold = (it == 0) ? 1.0f : r_lds[lrow];
                float rnew = rold / (rold * s + EPS);
                if (h == 0) r_lds[lrow] = rnew;
                pacc.x += q.x * rnew; pacc.y += q.y * rnew;
                pacc.z += q.z * rnew; pacc.w += q.w * rnew;
            }
        }

        // ---- block-level column reduction (fixed order), publish partials --
        plds[wib][lane] = pacc;
        __syncthreads();
        if (tid < NE) {
            const int hh = tid >> 2, kk = tid & 3;
            float t = 0.f;
#pragma unroll
            for (int w = 0; w < WPB; ++w)
#pragma unroll
                for (int gg = 0; gg < 4; ++gg)
                    t += ((const float*)&plds[w][gg * 16 + hh])[kk];
            __hip_atomic_store(&Pcur[blockIdx.x * NE + tid], t,
                               __ATOMIC_RELAXED, __HIP_MEMORY_SCOPE_AGENT);
        }
        __syncthreads();   // compiler drains vmcnt here -> partials complete

        // ---- grid barrier: relaxed polls, tid0-only fences ----------------
        if (tid == 0) {
            __builtin_amdgcn_fence(__ATOMIC_RELEASE, "agent");
            __hip_atomic_fetch_add(&counters[it], 1u, __ATOMIC_RELAXED,
                                   __HIP_MEMORY_SCOPE_AGENT);
            while (__hip_atomic_load(&counters[it], __ATOMIC_RELAXED,
                                     __HIP_MEMORY_SCOPE_AGENT) < (unsigned)NBLK)
                __builtin_amdgcn_s_sleep(2);
            __builtin_amdgcn_fence(__ATOMIC_ACQUIRE, "agent");
        }
        __syncthreads();

        // ---- every block reduces all partials in fixed order (determ.) ----
        {
            const int col = tid & 63;
            const int chunk = tid >> 6;          // 16 chunks of 32 blocks
            const int b0 = chunk * (NBLK / 16);
            float t = 0.f;
#pragma unroll
            for (int b2 = 0; b2 < NBLK / 16; ++b2)
                t += __hip_atomic_load(&Pcur[(b0 + b2) * NE + col],
                                       __ATOMIC_RELAXED,
                                       __HIP_MEMORY_SCOPE_AGENT);
            s_red[chunk][col] = t;
        }
        __syncthreads();
        if (tid < NE) {
            float P = 0.f;
#pragma unroll
            for (int k = 0; k < 16; ++k) P += s_red[k][tid];
            float cj = ((float*)c_lds4)[tid];
            ((float*)c_lds4)[tid] = cj * col_target / (cj * P + EPS);
        }
        __syncthreads();
    }

    // ---- final: row-normalize + top-2 (DPP argmax) + renorm ---------------
    {
        const float4 c4 = c_lds4[h];
        const int base_col = h * 4;

        float4 buf[PF];
#pragma unroll
        for (int p = 0; p < PF; ++p) buf[p] = lp[(size_t)p * 64];

        for (int b = 0; b < nb; ++b) {
            float4 cur[PF];
#pragma unroll
            for (int p = 0; p < PF; ++p) cur[p] = buf[p];
            if (b + 1 < nb) {
                const float4* np = lp + (size_t)(b + 1) * PF * 64;
#pragma unroll
                for (int p = 0; p < PF; ++p) buf[p] = np[(size_t)p * 64];
            }
#pragma unroll
            for (int p = 0; p < PF; ++p) {
                float4 u;
                u.x = __expf(cur[p].x) * c4.x; u.y = __expf(cur[p].y) * c4.y;
                u.z = __expf(cur[p].z) * c4.z; u.w = __expf(cur[p].w) * c4.w;
                float s = group16_sum(u.x + u.y + u.z + u.w);
                const int lrow = lrow0 + (b * PF + p) * 4;
                float rold = r_lds[lrow];
                float rnew = rold / (rold * s + EPS);
                float4 val;
                val.x = u.x * rnew; val.y = u.y * rnew;
                val.z = u.z * rnew; val.w = u.w * rnew;

                // top-1: per-lane best of 4 (lower col wins ties), group argmax
                float v = val.x; int i = base_col;
                if (val.y > v) { v = val.y; i = base_col + 1; }
                if (val.z > v) { v = val.z; i = base_col + 2; }
                if (val.w > v) { v = val.w; i = base_col + 3; }
                group16_argmax(v, i);
                float v1 = v; int i1 = i;

                float4 mv;
                mv.x = (i1 == base_col)     ? -INFINITY : val.x;
                mv.y = (i1 == base_col + 1) ? -INFINITY : val.y;
                mv.z = (i1 == base_col + 2) ? -INFINITY : val.z;
                mv.w = (i1 == base_col + 3) ? -INFINITY : val.w;
                v = mv.x; i = base_col;
                if (mv.y > v) { v = mv.y; i = base_col + 1; }
                if (mv.z > v) { v = mv.z; i = base_col + 2; }
                if (mv.w > v) { v = mv.w; i = base_col + 3; }
                group16_argmax(v, i);
                float v2 = v; int i2 = i;

                if (h == 0) {
                    int row = (qbase + b * PF + p) * 4 + g;
                    float wsum = v1 + v2 + EPS;
                    oidx[row] = make_float2((float)i1, (float)i2);
                    ow[row] = make_float2(v1 / wsum, v2 / wsum);
                }
            }
        }
    }
}

extern "C" void kernel_launch(void* const* d_in, const int* in_sizes, int n_in,
                              void* d_out, int out_size, void* d_ws, size_t ws_size,
                              hipStream_t stream) {
    const float* logits = (const float*)d_in[0];
    const int S = in_sizes[0] / NE;            // 524288
    const int nquads = S / 4;                  // 131072 (divisible by NWAVES)
    const float col_target = (float)S / (float)NE;

    float* Pblk = (float*)d_ws;                // 2*NBLK*64 floats (dbuf)
    unsigned* counters = (unsigned*)(Pblk + 2 * NBLK * NE);  // ITERS slots

    float* out = (float*)d_out;
    float2* oidx = (float2*)out;               // 2*S floats (indices)
    float2* ow = (float2*)(out + (size_t)2 * S);  // 2*S floats (weights)

    hipMemsetAsync(counters, 0, ITERS * sizeof(unsigned), stream);
    sink_fused<<<NBLK, TPB, 0, stream>>>((const float4*)logits, Pblk, counters,
                                         oidx, ow, nquads, col_target);
}

// Round 4
// 537.340 us; speedup vs baseline: 1.7251x; 1.7251x over previous
//
#include <hip/hip_runtime.h>
#include <math.h>

#define EPS 1e-6f
#define NE 64
#define TPB 1024
#define WPB 16             // waves per block
#define NBLK 256           // == CU count: 1 block/CU (R3 showed 2/CU regresses)
#define NWAVES (NBLK * WPB)   // 4096
#define ITERS 10
#define PF 8               // prefetch depth (quads in flight per wave)

// ---- DPP helpers: 16-lane-group reductions, pure VALU (no ds ops) ----
template <int ctrl>
__device__ __forceinline__ float dppf(float x) {
    return __int_as_float(__builtin_amdgcn_update_dpp(
        0, __float_as_int(x), ctrl, 0xf, 0xf, true));
}
template <int ctrl>
__device__ __forceinline__ int dppi(int x) {
    return __builtin_amdgcn_update_dpp(0, x, ctrl, 0xf, 0xf, true);
}

__device__ __forceinline__ float group16_sum(float v) {
    v += dppf<0xB1>(v);   // quad_perm xor 1
    v += dppf<0x4E>(v);   // quad_perm xor 2
    v += dppf<0x141>(v);  // row_half_mirror (xor 4)
    v += dppf<0x140>(v);  // row_mirror (xor 8)
    return v;
}

#define ARGMAX_STEP(CTRL)                                      \
    {                                                          \
        float ov = dppf<CTRL>(v);                              \
        int oi = dppi<CTRL>(i);                                \
        if (ov > v || (ov == v && oi < i)) { v = ov; i = oi; } \
    }

__device__ __forceinline__ void group16_argmax(float& v, int& i) {
    ARGMAX_STEP(0xB1)
    ARGMAX_STEP(0x4E)
    ARGMAX_STEP(0x141)
    ARGMAX_STEP(0x140)
}

// Persistent fused kernel, round 4.
// R3 post-mortem: 2 blocks/CU REGRESSED (403->800us, VALUBusy halved) --
// latency-bound per wave, not occupancy-starved. Back to R2 config.
// R4 changes (both attack per-wave MLP, arithmetic order unchanged):
//  - PF 4->8 with consume-reload (double outstanding loads, VGPR-lean)
//  - last batch's reload wraps to batch 0 => next iteration's first loads
//    are issued BEFORE the grid barrier; their latency hides under the
//    barrier wait instead of stalling the iteration start.
__global__ __launch_bounds__(TPB, 4) void sink_fused(
    const float4* __restrict__ logits4,
    float* __restrict__ Pblk,          // [2][NBLK][NE]
    unsigned* __restrict__ counters,   // [ITERS]
    float2* __restrict__ oidx, float2* __restrict__ ow,
    int nquads, float col_target) {
    __shared__ float4 plds[WPB][64];   // 16 KB  block column-partial buffer
    __shared__ float s_red[16][NE];    // 4 KB   chunk-reduce buffer
    __shared__ float r_lds[WPB * 128]; // 8 KB   per-row r (2048 rows/block)
    __shared__ float4 c_lds4[NE / 4];  // 256 B  current column scaling

    const int tid = threadIdx.x;
    const int lane = tid & 63;
    const int wib = tid >> 6;
    const int g = lane >> 4;   // row within quad
    const int h = lane & 15;   // float4 slot within row
    const int qpw = nquads / NWAVES;                 // 32
    const int qbase = (blockIdx.x * WPB + wib) * qpw;
    const float4* lp = logits4 + (size_t)qbase * 64 + lane;
    const int nb = qpw / PF;                         // 4
    const int lrow0 = wib * 128 + g;

    if (tid < NE / 4) c_lds4[tid] = make_float4(1.f, 1.f, 1.f, 1.f);

    // prologue: first batch in flight before the first iteration
    float4 buf[PF];
#pragma unroll
    for (int p = 0; p < PF; ++p) buf[p] = lp[(size_t)p * 64];
    __syncthreads();

    for (int it = 0; it < ITERS; ++it) {
        const float4 c4 = c_lds4[h];
        float* Pcur = Pblk + (size_t)(it & 1) * NBLK * NE;

        float4 pacc = {0.f, 0.f, 0.f, 0.f};
        for (int b = 0; b < nb; ++b) {
            // reload target: next batch, wrapping to batch 0 so that the
            // next iteration's (or final phase's) first loads are already
            // in flight across the grid barrier.
            const int nxt = (b + 1 < nb) ? (b + 1) * PF : 0;
            const float4* np = lp + (size_t)nxt * 64;
#pragma unroll
            for (int p = 0; p < PF; ++p) {
                const float4 cur = buf[p];
                buf[p] = np[(size_t)p * 64];
                float4 q;
                q.x = __expf(cur.x); q.y = __expf(cur.y);
                q.z = __expf(cur.z); q.w = __expf(cur.w);
                float s = q.x * c4.x + q.y * c4.y + q.z * c4.z + q.w * c4.w;
                s = group16_sum(s);
                const int lrow = lrow0 + (b * PF + p) * 4;
                float rold = (it == 0) ? 1.0f : r_lds[lrow];
                float rnew = rold / (rold * s + EPS);
                if (h == 0) r_lds[lrow] = rnew;
                pacc.x += q.x * rnew; pacc.y += q.y * rnew;
                pacc.z += q.z * rnew; pacc.w += q.w * rnew;
            }
        }

        // ---- block-level column reduction (fixed order), publish partials --
        plds[wib][lane] = pacc;
        __syncthreads();
        if (tid < NE) {
            const int hh = tid >> 2, kk = tid & 3;
            float t = 0.f;
#pragma unroll
            for (int w = 0; w < WPB; ++w)
#pragma unroll
                for (int gg = 0; gg < 4; ++gg)
                    t += ((const float*)&plds[w][gg * 16 + hh])[kk];
            __hip_atomic_store(&Pcur[blockIdx.x * NE + tid], t,
                               __ATOMIC_RELAXED, __HIP_MEMORY_SCOPE_AGENT);
        }
        __syncthreads();   // partials drained before arrival

        // ---- grid barrier: relaxed polls, tid0-only fences ----------------
        if (tid == 0) {
            __builtin_amdgcn_fence(__ATOMIC_RELEASE, "agent");
            __hip_atomic_fetch_add(&counters[it], 1u, __ATOMIC_RELAXED,
                                   __HIP_MEMORY_SCOPE_AGENT);
            while (__hip_atomic_load(&counters[it], __ATOMIC_RELAXED,
                                     __HIP_MEMORY_SCOPE_AGENT) < (unsigned)NBLK)
                __builtin_amdgcn_s_sleep(2);
            __builtin_amdgcn_fence(__ATOMIC_ACQUIRE, "agent");
        }
        __syncthreads();

        // ---- every block reduces all partials in fixed order (determ.) ----
        {
            const int col = tid & 63;
            const int chunk = tid >> 6;          // 16 chunks of 16 blocks
            const int b0 = chunk * (NBLK / 16);
            float t = 0.f;
#pragma unroll
            for (int b2 = 0; b2 < NBLK / 16; ++b2)
                t += __hip_atomic_load(&Pcur[(b0 + b2) * NE + col],
                                       __ATOMIC_RELAXED,
                                       __HIP_MEMORY_SCOPE_AGENT);
            s_red[chunk][col] = t;
        }
        __syncthreads();
        if (tid < NE) {
            float P = 0.f;
#pragma unroll
            for (int k = 0; k < 16; ++k) P += s_red[k][tid];
            float cj = ((float*)c_lds4)[tid];
            ((float*)c_lds4)[tid] = cj * col_target / (cj * P + EPS);
        }
        __syncthreads();
    }

    // ---- final: row-normalize + top-2 (DPP argmax) + renorm ---------------
    // buf already holds batch 0 (loaded during the last iteration's wrap).
    {
        const float4 c4 = c_lds4[h];
        const int base_col = h * 4;

        for (int b = 0; b < nb; ++b) {
            const bool more = (b + 1 < nb);
            const float4* np = lp + (size_t)(b + 1) * PF * 64;
#pragma unroll
            for (int p = 0; p < PF; ++p) {
                const float4 cur = buf[p];
                if (more) buf[p] = np[(size_t)p * 64];
                float4 u;
                u.x = __expf(cur.x) * c4.x; u.y = __expf(cur.y) * c4.y;
                u.z = __expf(cur.z) * c4.z; u.w = __expf(cur.w) * c4.w;
                float s = group16_sum(u.x + u.y + u.z + u.w);
                const int lrow = lrow0 + (b * PF + p) * 4;
                float rold = r_lds[lrow];
                float rnew = rold / (rold * s + EPS);
                float4 val;
                val.x = u.x * rnew; val.y = u.y * rnew;
                val.z = u.z * rnew; val.w = u.w * rnew;

                // top-1: per-lane best of 4 (lower col wins ties), group argmax
                float v = val.x; int i = base_col;
                if (val.y > v) { v = val.y; i = base_col + 1; }
                if (val.z > v) { v = val.z; i = base_col + 2; }
                if (val.w > v) { v = val.w; i = base_col + 3; }
                group16_argmax(v, i);
                float v1 = v; int i1 = i;

                float4 mv;
                mv.x = (i1 == base_col)     ? -INFINITY : val.x;
                mv.y = (i1 == base_col + 1) ? -INFINITY : val.y;
                mv.z = (i1 == base_col + 2) ? -INFINITY : val.z;
                mv.w = (i1 == base_col + 3) ? -INFINITY : val.w;
                v = mv.x; i = base_col;
                if (mv.y > v) { v = mv.y; i = base_col + 1; }
                if (mv.z > v) { v = mv.z; i = base_col + 2; }
                if (mv.w > v) { v = mv.w; i = base_col + 3; }
                group16_argmax(v, i);
                float v2 = v; int i2 = i;

                if (h == 0) {
                    int row = (qbase + b * PF + p) * 4 + g;
                    float wsum = v1 + v2 + EPS;
                    oidx[row] = make_float2((float)i1, (float)i2);
                    ow[row] = make_float2(v1 / wsum, v2 / wsum);
                }
            }
        }
    }
}

extern "C" void kernel_launch(void* const* d_in, const int* in_sizes, int n_in,
                              void* d_out, int out_size, void* d_ws, size_t ws_size,
                              hipStream_t stream) {
    const float* logits = (const float*)d_in[0];
    const int S = in_sizes[0] / NE;            // 524288
    const int nquads = S / 4;                  // 131072 (divisible by NWAVES)
    const float col_target = (float)S / (float)NE;

    float* Pblk = (float*)d_ws;                // 2*NBLK*64 floats (dbuf)
    unsigned* counters = (unsigned*)(Pblk + 2 * NBLK * NE);  // ITERS slots

    float* out = (float*)d_out;
    float2* oidx = (float2*)out;               // 2*S floats (indices)
    float2* ow = (float2*)(out + (size_t)2 * S);  // 2*S floats (weights)

    hipMemsetAsync(counters, 0, ITERS * sizeof(unsigned), stream);
    sink_fused<<<NBLK, TPB, 0, stream>>>((const float4*)logits, Pblk, counters,
                                         oidx, ow, nquads, col_target);
}